// Round 12
// baseline (135.638 us; speedup 1.0000x reference)
//
#include <hip/hip_runtime.h>
#include <math.h>

#define Bn 2048
#define Dd 128
#define Cc 50000
#define ASPL 96     // arc col-splits (16-col chunks, strided); 32 rg x 96 = 3072 waves
#define NCH 33      // fixed chunk-loop count (3125 = 96*32 + 53)
#define TS 32       // triplet col-splits (64 cols each)

#define COS_Mf 0.8775825618903728f
#define SIN_Mf 0.479425538604203f
#define THf (-0.8775825618903728f)
#define MMf 0.2397127693021015f
#define L2E64 92.33248261689366f   // 64 * log2(e)

typedef __attribute__((ext_vector_type(8))) short short8;
typedef __attribute__((ext_vector_type(4))) float f32x4;

__device__ __forceinline__ unsigned short f2bf(float f) {
    unsigned int u = __float_as_uint(f);
    u += 0x7fffu + ((u >> 16) & 1u);
    return (unsigned short)(u >> 16);
}
__device__ __forceinline__ float bf2f(unsigned short h) {
    return __uint_as_float(((unsigned int)h) << 16);
}

// ---------------- row normalization -> bf16, float4-vectorized (8 rows/block) ----------------
__global__ void norm_all(const float* __restrict__ emb, const float* __restrict__ W,
                         unsigned short* __restrict__ embn, unsigned short* __restrict__ rawb,
                         float* __restrict__ sqn, unsigned short* __restrict__ wnb,
                         float* __restrict__ zp) {
    if (blockIdx.x == 0) zp[threadIdx.x] = 0.f;    // esum|wsum (256 floats)
    int wid = threadIdx.x >> 6;
    int lane = threadIdx.x & 63;
    int half = lane >> 5, l32 = lane & 31;
    int row = blockIdx.x * 8 + wid * 2 + half;
    bool ise = row < Bn;
    int r = ise ? row : row - Bn;
    const float* p = (ise ? emb : W) + (size_t)r * Dd + l32 * 4;
    float4 v = *reinterpret_cast<const float4*>(p);
    float ss = v.x * v.x + v.y * v.y + v.z * v.z + v.w * v.w;
    #pragma unroll
    for (int o = 16; o > 0; o >>= 1) ss += __shfl_xor(ss, o);   // stays within 32-lane half
    float rn = rsqrtf(ss);
    ushort4 q4 = make_ushort4(f2bf(v.x * rn), f2bf(v.y * rn), f2bf(v.z * rn), f2bf(v.w * rn));
    *reinterpret_cast<ushort4*>((ise ? embn : wnb) + (size_t)r * Dd + l32 * 4) = q4;
    if (ise) {
        ushort4 r4 = make_ushort4(f2bf(v.x), f2bf(v.y), f2bf(v.z), f2bf(v.w));
        *reinterpret_cast<ushort4*>(rawb + (size_t)r * Dd + l32 * 4) = r4;
        if (l32 == 0) sqn[r] = ss;
    }
}

// ---------------- column sums (blocks 0..271) + per-row label logits (blocks 272..783) ----------------
__global__ void aux_k(const unsigned short* __restrict__ embn,
                      const unsigned short* __restrict__ wnb,
                      const int* __restrict__ lab,
                      float* __restrict__ esum, float* __restrict__ wsum,
                      float* __restrict__ bx, float* __restrict__ tg) {
    __shared__ float s[16][128];
    int t = threadIdx.x;
    if (blockIdx.x < 272) {
        int rg = t >> 4;
        int cg = (t & 15) * 8;
        const unsigned short* src;
        float* dst;
        int r0, rend;
        if (blockIdx.x < 256) {
            src = wnb; dst = wsum;
            r0 = blockIdx.x * 196;
            rend = r0 + 196; if (rend > Cc) rend = Cc;
        } else {
            src = embn; dst = esum;
            r0 = (blockIdx.x - 256) * 128;
            rend = r0 + 128;
        }
        float acc[8];
        #pragma unroll
        for (int j = 0; j < 8; ++j) acc[j] = 0.f;
        for (int r = r0 + rg; r < rend; r += 16) {
            short8 v = *reinterpret_cast<const short8*>(src + (size_t)r * Dd + cg);
            #pragma unroll
            for (int j = 0; j < 8; ++j) acc[j] += bf2f((unsigned short)v[j]);
        }
        #pragma unroll
        for (int j = 0; j < 8; ++j) s[rg][cg + j] = acc[j];
        __syncthreads();
        if (t < 128) {
            float v = 0.f;
            #pragma unroll
            for (int u = 0; u < 16; ++u) v += s[u][t];
            atomicAdd(&dst[t], v);
        }
    } else {
        int wid = t >> 6, lane = t & 63;
        int row = (blockIdx.x - 272) * 4 + wid;
        int lb = lab[row];
        const unsigned short* e = embn + (size_t)row * Dd;
        const unsigned short* wv = wnb + (size_t)lb * Dd;
        float sv = bf2f(e[lane]) * bf2f(wv[lane]) + bf2f(e[lane + 64]) * bf2f(wv[lane + 64]);
        #pragma unroll
        for (int o = 32; o > 0; o >>= 1) sv += __shfl_xor(sv, o);
        if (lane == 0) {
            float c = sv;
            float s2 = fminf(fmaxf(1.f - c * c, 0.f), 1.f);
            float sine = sqrtf(s2);
            float phi = c * COS_Mf - sine * SIN_Mf;
            phi = (c > THf) ? phi : (c - MMf);
            bx[row] = 64.f * c;
            tg[row] = 64.f * phi;
        }
    }
}

// ---------------- fused bf16-MFMA cosine-GEMM + fixed-max softmax partials ----------------
// Barrier-free, LDS-free, depth-2 register prefetch (3 rotating B buffers, static names).
// 3072 waves = 32 row-groups (64 rows each) x 96 col-splits; 768 blocks = 3/CU exactly.
// Wave: A panel 64x128 in VGPRs (afrag[4][4]); B 16-col chunk -> regs, frag layout
// col=l&15, k=(l>>4)*8+kc*32. Block's 4 waves share split -> L1 reuse.
#define LOADB(B, p) {                                        \
    B[0] = *reinterpret_cast<const short8*>(p);              \
    B[1] = *reinterpret_cast<const short8*>((p) + 32);       \
    B[2] = *reinterpret_cast<const short8*>((p) + 64);       \
    B[3] = *reinterpret_cast<const short8*>((p) + 96); }

#define COMPUTE(B) {                                                          \
    f32x4 acc_[4];                                                            \
    _Pragma("unroll")                                                         \
    for (int sm_ = 0; sm_ < 4; ++sm_) acc_[sm_] = (f32x4){0.f, 0.f, 0.f, 0.f};\
    _Pragma("unroll")                                                         \
    for (int kc_ = 0; kc_ < 4; ++kc_) {                                       \
        _Pragma("unroll")                                                     \
        for (int sm_ = 0; sm_ < 4; ++sm_)                                     \
            acc_[sm_] = __builtin_amdgcn_mfma_f32_16x16x32_bf16(              \
                afrag[sm_][kc_], B[kc_], acc_[sm_], 0, 0, 0);                 \
    }                                                                         \
    _Pragma("unroll")                                                         \
    for (int sm_ = 0; sm_ < 4; ++sm_)                                         \
        _Pragma("unroll")                                                     \
        for (int r_ = 0; r_ < 4; ++r_)                                        \
            sacc[sm_][r_] += __builtin_amdgcn_exp2f(                          \
                fmaf(acc_[sm_][r_], L2E64, -L2E64)); }

// compute chunk i from Bc, load chunk i+2 into Bl (clamped addr, guarded accum)
#define STEP(Bc, Bl, i) {                                                     \
    if ((i) + 2 < NCH) {                                                      \
        int ic_ = ((i) + 2 < nch) ? (i) + 2 : nch - 1;                        \
        LOADB(Bl, base + (size_t)ic_ * CSTEP);                                \
    }                                                                         \
    if ((i) < nch) { COMPUTE(Bc); } }

__launch_bounds__(256, 3)
__global__ void arc_main(const unsigned short* __restrict__ en,
                         const unsigned short* __restrict__ wn,
                         float* __restrict__ ps) {
    const int t = threadIdx.x;
    const int w = t >> 6, l = t & 63;
    const int wid = blockIdx.x * 4 + w;
    const int split = wid >> 5;      // 0..95 (shared by the block's 4 waves)
    const int rg = wid & 31;         // 0..31
    const int lc = l & 15, lk = l >> 4;

    // A panel: 64 rows x 128 k
    short8 afrag[4][4];
    #pragma unroll
    for (int sm = 0; sm < 4; ++sm)
        #pragma unroll
        for (int kc = 0; kc < 4; ++kc)
            afrag[sm][kc] = *reinterpret_cast<const short8*>(
                en + (size_t)(rg * 64 + sm * 16 + lc) * Dd + kc * 32 + lk * 8);

    float sacc[4][4];
    #pragma unroll
    for (int sm = 0; sm < 4; ++sm)
        #pragma unroll
        for (int r = 0; r < 4; ++r) sacc[sm][r] = 0.f;

    const int nch = (split < 53) ? 33 : 32;        // 3125 = 96*32 + 53
    const unsigned short* base = wn + ((size_t)(split * 16 + lc) << 7) + lk * 8;
    const size_t CSTEP = (size_t)ASPL * 16 * 128;  // 96 splits x 16 cols x 128 el

    short8 bA[4], bB[4], bC[4];
    LOADB(bA, base);
    LOADB(bB, base + CSTEP);
    for (int ii = 0; ii < NCH; ii += 3) {          // 33 = 3 x 11, clean rotation
        STEP(bA, bC, ii);
        STEP(bB, bA, ii + 1);
        STEP(bC, bB, ii + 2);
    }

    // reduce over the wave's 16 col-lanes; C/D layout: col=l&15, row=(l>>4)*4+r
    #pragma unroll
    for (int sm = 0; sm < 4; ++sm)
        #pragma unroll
        for (int r = 0; r < 4; ++r) {
            float v = sacc[sm][r];
            v += __shfl_xor(v, 1); v += __shfl_xor(v, 2);
            v += __shfl_xor(v, 4); v += __shfl_xor(v, 8);
            sacc[sm][r] = v;
        }
    if (lc == 0) {
        #pragma unroll
        for (int sm = 0; sm < 4; ++sm)
            #pragma unroll
            for (int r = 0; r < 4; ++r)
                ps[(size_t)split * Bn + rg * 64 + sm * 16 + lk * 4 + r] = sacc[sm][r];
    }
}

// ---------------- batch-hard triplet: bf16 MFMA self-GEMM + masked max/min ----------------
// (R11-proven version, verbatim)
__launch_bounds__(256, 2)
__global__ void trip_k(const unsigned short* __restrict__ eb, const float* __restrict__ sqn,
                       const int* __restrict__ lab,
                       float* __restrict__ hp, float* __restrict__ hn,
                       float* __restrict__ cnt) {
    __shared__ unsigned short swt[8192];      // 16KB: one 64-col tile, XOR-swizzled
    __shared__ float red[128][2][3];
    const int t = threadIdx.x;
    const int w = t >> 6, l = t & 63;
    const int r0 = blockIdx.x * 128;
    const int split = blockIdx.y;
    const int c0 = split * 64;
    const int rowbase = r0 + (w & 1) * 64;
    const int colb = (w >> 1) * 32;

    #pragma unroll
    for (int j = 0; j < 4; ++j) {
        int col = (w * 4 + j) * 4 + (l >> 4);
        int kb = ((l & 15) * 16) ^ ((col & 7) << 4);
        const unsigned short* src = eb + ((size_t)(c0 + col) << 7) + (kb >> 1);
        __builtin_amdgcn_global_load_lds(
            (const __attribute__((address_space(1))) void*)src,
            (__attribute__((address_space(3))) void*)(&swt[(w * 4 + j) * 512]),
            16, 0, 0);
    }

    short8 afrag[4][4];
    #pragma unroll
    for (int sm = 0; sm < 4; ++sm)
        #pragma unroll
        for (int kc = 0; kc < 4; ++kc) {
            int row = rowbase + sm * 16 + (l & 15);
            int k0 = kc * 32 + (l >> 4) * 8;
            afrag[sm][kc] = *reinterpret_cast<const short8*>(eb + (size_t)row * Dd + k0);
        }

    float rsq[4][4]; int rlb[4][4];
    #pragma unroll
    for (int sm = 0; sm < 4; ++sm)
        #pragma unroll
        for (int r = 0; r < 4; ++r) {
            int row = rowbase + sm * 16 + (l >> 4) * 4 + r;
            rsq[sm][r] = sqn[row];
            rlb[sm][r] = lab[row];
        }
    int cj[2]; float csq[2]; int clb[2];
    #pragma unroll
    for (int sn = 0; sn < 2; ++sn) {
        cj[sn] = c0 + colb + sn * 16 + (l & 15);
        csq[sn] = sqn[cj[sn]];
        clb[sn] = lab[cj[sn]];
    }

    __syncthreads();

    f32x4 acc[4][2];
    #pragma unroll
    for (int sm = 0; sm < 4; ++sm)
        #pragma unroll
        for (int sn = 0; sn < 2; ++sn)
            acc[sm][sn] = (f32x4){0.f, 0.f, 0.f, 0.f};

    #pragma unroll
    for (int kc = 0; kc < 4; ++kc) {
        short8 bfr[2];
        #pragma unroll
        for (int sn = 0; sn < 2; ++sn) {
            int rcol = colb + sn * 16 + (l & 15);
            int rkb = (kc * 64 + (l >> 4) * 16) ^ ((rcol & 7) << 4);
            bfr[sn] = *reinterpret_cast<const short8*>(swt + rcol * 128 + (rkb >> 1));
        }
        #pragma unroll
        for (int sn = 0; sn < 2; ++sn)
            #pragma unroll
            for (int sm = 0; sm < 4; ++sm)
                acc[sm][sn] = __builtin_amdgcn_mfma_f32_16x16x32_bf16(
                    afrag[sm][kc], bfr[sn], acc[sm][sn], 0, 0, 0);
    }

    float vhp[4][4], vhn[4][4], vct[4][4];
    #pragma unroll
    for (int sm = 0; sm < 4; ++sm)
        #pragma unroll
        for (int r = 0; r < 4; ++r) { vhp[sm][r] = 0.f; vhn[sm][r] = 1e30f; vct[sm][r] = 0.f; }

    #pragma unroll
    for (int sm = 0; sm < 4; ++sm)
        #pragma unroll
        for (int r = 0; r < 4; ++r) {
            int rg = rowbase + sm * 16 + (l >> 4) * 4 + r;
            #pragma unroll
            for (int sn = 0; sn < 2; ++sn) {
                float d2 = fmaf(acc[sm][sn][r], -2.f, rsq[sm][r] + csq[sn]);
                float dist = sqrtf(fmaxf(d2, 0.f) + 1e-16f);
                bool same = (rlb[sm][r] == clb[sn]);
                bool psel = same && (rg != cj[sn]);
                if (psel) { vhp[sm][r] = fmaxf(vhp[sm][r], dist); vct[sm][r] += 1.f; }
                if (!same) vhn[sm][r] = fminf(vhn[sm][r], dist);
            }
        }

    #pragma unroll
    for (int sm = 0; sm < 4; ++sm)
        #pragma unroll
        for (int r = 0; r < 4; ++r) {
            float a = vhp[sm][r], b = vhn[sm][r], c = vct[sm][r];
            #pragma unroll
            for (int o = 1; o < 16; o <<= 1) {
                a = fmaxf(a, __shfl_xor(a, o));
                b = fminf(b, __shfl_xor(b, o));
                c += __shfl_xor(c, o);
            }
            if ((l & 15) == 0) {
                int row = (w & 1) * 64 + sm * 16 + (l >> 4) * 4 + r;
                red[row][w >> 1][0] = a;
                red[row][w >> 1][1] = b;
                red[row][w >> 1][2] = c;
            }
        }
    __syncthreads();
    if (t < 128) {
        float a = fmaxf(red[t][0][0], red[t][1][0]);
        float b = fminf(red[t][0][1], red[t][1][1]);
        float c = red[t][0][2] + red[t][1][2];
        hp[(size_t)split * Bn + r0 + t] = a;
        hn[(size_t)split * Bn + r0 + t] = b;
        cnt[(size_t)split * Bn + r0 + t] = c;
    }
}

// ---------------- per-row merge -> per-block partials (no atomics) ----------------
__launch_bounds__(256)
__global__ void final_k(const float* __restrict__ ps, const float* __restrict__ bx,
                        const float* __restrict__ tg, const float* __restrict__ hp,
                        const float* __restrict__ hn, const float* __restrict__ cnt,
                        float* __restrict__ gpart) {
    __shared__ float sA[4], sT[4], sV[4];
    int row = blockIdx.x * 256 + threadIdx.x;
    float s = 0.f;
    for (int u = 0; u < ASPL; ++u) s += ps[(size_t)u * Bn + row];
    float base = bx[row], targ = tg[row];
    s += __expf(targ - 64.f) - __expf(base - 64.f);
    float lse = 64.f + logf(s);
    float arcs = lse - 0.9f * targ - 0.1f * (targ - base) / (float)Cc;

    float a = 0.f, b = 1e30f, c = 0.f;
    for (int u = 0; u < TS; ++u) {
        a = fmaxf(a, hp[(size_t)u * Bn + row]);
        b = fminf(b, hn[(size_t)u * Bn + row]);
        c += cnt[(size_t)u * Bn + row];
    }
    float tl = fmaxf(a - b + 0.3f, 0.f);
    float tris = (c > 0.f) ? tl : 0.f;
    float vals = (c > 0.f) ? 1.f : 0.f;

    #pragma unroll
    for (int o = 32; o > 0; o >>= 1) {
        arcs += __shfl_xor(arcs, o);
        tris += __shfl_xor(tris, o);
        vals += __shfl_xor(vals, o);
    }
    int wid = threadIdx.x >> 6, lane = threadIdx.x & 63;
    if (lane == 0) { sA[wid] = arcs; sT[wid] = tris; sV[wid] = vals; }
    __syncthreads();
    if (threadIdx.x == 0) {
        gpart[blockIdx.x * 3 + 0] = sA[0] + sA[1] + sA[2] + sA[3];
        gpart[blockIdx.x * 3 + 1] = sT[0] + sT[1] + sT[2] + sT[3];
        gpart[blockIdx.x * 3 + 2] = sV[0] + sV[1] + sV[2] + sV[3];
    }
}

// ---------------- scalar finish ----------------
__global__ void final2_k(const float* __restrict__ gpart, const float* __restrict__ es,
                         const float* __restrict__ wsum, float* __restrict__ out) {
    int l = threadIdx.x;   // 64
    float x = es[l] * wsum[l] + es[l + 64] * wsum[l + 64];
    #pragma unroll
    for (int o = 32; o > 0; o >>= 1) x += __shfl_xor(x, o);
    if (l == 0) {
        float A = 0.f, T = 0.f, V = 0.f;
        for (int b = 0; b < Bn / 256; ++b) {
            A += gpart[b * 3 + 0];
            T += gpart[b * 3 + 1];
            V += gpart[b * 3 + 2];
        }
        float tri = (V > 0.f) ? (T / fmaxf(V, 1.f)) : 0.f;
        out[0] = (A - 6.4f * x / (float)Cc) / (float)Bn + 0.5f * tri;
    }
}

extern "C" void kernel_launch(void* const* d_in, const int* in_sizes, int n_in,
                              void* d_out, int out_size, void* d_ws, size_t ws_size,
                              hipStream_t stream) {
    const float* emb = (const float*)d_in[0];
    const float* W = (const float*)d_in[1];
    const int* lab = (const int*)d_in[2];
    float* out = (float*)d_out;

    unsigned short* embn = (unsigned short*)d_ws;          // 2048*128 bf16
    unsigned short* rawb = embn + (size_t)Bn * Dd;         // 2048*128 bf16
    unsigned short* wnb = rawb + (size_t)Bn * Dd;          // 50000*128 bf16
    float* sqn = (float*)(wnb + (size_t)Cc * Dd);          // 2048
    float* ps = sqn + Bn;                                  // ASPL*2048
    float* bx = ps + (size_t)ASPL * Bn;                    // 2048
    float* tg = bx + Bn;                                   // 2048
    float* hp = tg + Bn;                                   // TS*2048
    float* hn = hp + (size_t)TS * Bn;                      // TS*2048
    float* ct = hn + (size_t)TS * Bn;                      // TS*2048
    float* esum = ct + (size_t)TS * Bn;                    // 128
    float* wsum = esum + 128;                              // 128
    float* gpart = wsum + 128;                             // 24

    norm_all<<<256 + Cc / 8, 256, 0, stream>>>(emb, W, embn, rawb, sqn, wnb, esum);
    aux_k<<<272 + Bn / 4, 256, 0, stream>>>(embn, wnb, lab, esum, wsum, bx, tg);
    arc_main<<<768, 256, 0, stream>>>(embn, wnb, ps);
    trip_k<<<dim3(16, TS), 256, 0, stream>>>(rawb, sqn, lab, hp, hn, ct);
    final_k<<<Bn / 256, 256, 0, stream>>>(ps, bx, tg, hp, hn, ct, gpart);
    final2_k<<<1, 64, 0, stream>>>(gpart, esum, wsum, out);
}

// Round 13
// 83.154 us; speedup vs baseline: 1.6312x; 1.6312x over previous
//
#include <hip/hip_runtime.h>
#include <math.h>

#define Bn 2048
#define Dd 128
#define Cc 50000
#define NSPL 24     // arc col-splits; grid (32 row-blocks x 24) = 768 = 3/CU exact
#define NTILE 782   // ceil(50000/64)
#define TS 32       // triplet col-splits (64 cols each)

#define COS_Mf 0.8775825618903728f
#define SIN_Mf 0.479425538604203f
#define THf (-0.8775825618903728f)
#define MMf 0.2397127693021015f
#define L2E64 92.33248261689366f   // 64 * log2(e)

typedef __attribute__((ext_vector_type(8))) short short8;
typedef __attribute__((ext_vector_type(4))) float f32x4;

__device__ __forceinline__ unsigned short f2bf(float f) {
    unsigned int u = __float_as_uint(f);
    u += 0x7fffu + ((u >> 16) & 1u);
    return (unsigned short)(u >> 16);
}
__device__ __forceinline__ float bf2f(unsigned short h) {
    return __uint_as_float(((unsigned int)h) << 16);
}

// ---------------- row normalization -> bf16, float4-vectorized (8 rows/block) ----------------
__global__ void norm_all(const float* __restrict__ emb, const float* __restrict__ W,
                         unsigned short* __restrict__ embn, unsigned short* __restrict__ rawb,
                         float* __restrict__ sqn, unsigned short* __restrict__ wnb,
                         float* __restrict__ zp) {
    if (blockIdx.x == 0) zp[threadIdx.x] = 0.f;    // esum|wsum (256 floats)
    int wid = threadIdx.x >> 6;
    int lane = threadIdx.x & 63;
    int half = lane >> 5, l32 = lane & 31;
    int row = blockIdx.x * 8 + wid * 2 + half;
    bool ise = row < Bn;
    int r = ise ? row : row - Bn;
    const float* p = (ise ? emb : W) + (size_t)r * Dd + l32 * 4;
    float4 v = *reinterpret_cast<const float4*>(p);
    float ss = v.x * v.x + v.y * v.y + v.z * v.z + v.w * v.w;
    #pragma unroll
    for (int o = 16; o > 0; o >>= 1) ss += __shfl_xor(ss, o);   // stays within 32-lane half
    float rn = rsqrtf(ss);
    ushort4 q4 = make_ushort4(f2bf(v.x * rn), f2bf(v.y * rn), f2bf(v.z * rn), f2bf(v.w * rn));
    *reinterpret_cast<ushort4*>((ise ? embn : wnb) + (size_t)r * Dd + l32 * 4) = q4;
    if (ise) {
        ushort4 r4 = make_ushort4(f2bf(v.x), f2bf(v.y), f2bf(v.z), f2bf(v.w));
        *reinterpret_cast<ushort4*>(rawb + (size_t)r * Dd + l32 * 4) = r4;
        if (l32 == 0) sqn[r] = ss;
    }
}

// ---------------- column sums (blocks 0..271) + per-row label logits (blocks 272..783) ----------------
__global__ void aux_k(const unsigned short* __restrict__ embn,
                      const unsigned short* __restrict__ wnb,
                      const int* __restrict__ lab,
                      float* __restrict__ esum, float* __restrict__ wsum,
                      float* __restrict__ bx, float* __restrict__ tg) {
    __shared__ float s[16][128];
    int t = threadIdx.x;
    if (blockIdx.x < 272) {
        int rg = t >> 4;
        int cg = (t & 15) * 8;
        const unsigned short* src;
        float* dst;
        int r0, rend;
        if (blockIdx.x < 256) {
            src = wnb; dst = wsum;
            r0 = blockIdx.x * 196;
            rend = r0 + 196; if (rend > Cc) rend = Cc;
        } else {
            src = embn; dst = esum;
            r0 = (blockIdx.x - 256) * 128;
            rend = r0 + 128;
        }
        float acc[8];
        #pragma unroll
        for (int j = 0; j < 8; ++j) acc[j] = 0.f;
        for (int r = r0 + rg; r < rend; r += 16) {
            short8 v = *reinterpret_cast<const short8*>(src + (size_t)r * Dd + cg);
            #pragma unroll
            for (int j = 0; j < 8; ++j) acc[j] += bf2f((unsigned short)v[j]);
        }
        #pragma unroll
        for (int j = 0; j < 8; ++j) s[rg][cg + j] = acc[j];
        __syncthreads();
        if (t < 128) {
            float v = 0.f;
            #pragma unroll
            for (int u = 0; u < 16; ++u) v += s[u][t];
            atomicAdd(&dst[t], v);
        }
    } else {
        int wid = t >> 6, lane = t & 63;
        int row = (blockIdx.x - 272) * 4 + wid;
        int lb = lab[row];
        const unsigned short* e = embn + (size_t)row * Dd;
        const unsigned short* wv = wnb + (size_t)lb * Dd;
        float sv = bf2f(e[lane]) * bf2f(wv[lane]) + bf2f(e[lane + 64]) * bf2f(wv[lane + 64]);
        #pragma unroll
        for (int o = 32; o > 0; o >>= 1) sv += __shfl_xor(sv, o);
        if (lane == 0) {
            float c = sv;
            float s2 = fminf(fmaxf(1.f - c * c, 0.f), 1.f);
            float sine = sqrtf(s2);
            float phi = c * COS_Mf - sine * SIN_Mf;
            phi = (c > THf) ? phi : (c - MMf);
            bx[row] = 64.f * c;
            tg[row] = 64.f * phi;
        }
    }
}

// ---------------- fused bf16-MFMA cosine-GEMM + fixed-max softmax partials ----------------
// Per-wave private async pipeline: NO __syncthreads in the K-loop. Each wave stages
// ONLY its own 16-col strip into its own LDS region via global_load_lds (4 loads/tile),
// synchronized by counted s_waitcnt vmcnt(4). Block: 4 waves x (64 rows x 16-col strip).
// grid (32 row-blocks of 64, NSPL=24 splits) = 768 blocks = 3/CU.
__launch_bounds__(256, 3)
__global__ void arc_main(const unsigned short* __restrict__ en,
                         const unsigned short* __restrict__ wn,
                         float* __restrict__ ps) {
    __shared__ unsigned short swb[4][2][2048];   // [wave][buf][16 cols x 128 k], XOR-swizzled
    __shared__ float sred[4][64];
    const int t = threadIdx.x;
    const int w = t >> 6, l = t & 63;
    const int r0 = blockIdx.x * 64;
    const int split = blockIdx.y;
    const int strip = w * 16;                    // wave's 16-col strip within each 64-col tile
    const int lc = l & 15, lk = l >> 4;

    // A panel: 64 rows x 128 k (frag: row=lc, k=lk*8 within kc*32)
    short8 afrag[4][4];
    #pragma unroll
    for (int sm = 0; sm < 4; ++sm)
        #pragma unroll
        for (int kc = 0; kc < 4; ++kc)
            afrag[sm][kc] = *reinterpret_cast<const short8*>(
                en + (size_t)(r0 + sm * 16 + lc) * Dd + kc * 32 + lk * 8);

    float sacc[4][4];
    #pragma unroll
    for (int sm = 0; sm < 4; ++sm)
        #pragma unroll
        for (int r = 0; r < 4; ++r) sacc[sm][r] = 0.f;

    const int ntm = (NTILE - 1 - split) / NSPL + 1;

    // stage wave's strip of tile idx into swb[w][buf]; dest linear (lane*16),
    // source pre-swizzled: lane lk picks col, lane lc picks k-chunk (rule-21 pair).
    auto STAGE = [&](int buf, int idx) {
        int tl = split + idx * NSPL;
        if (tl > NTILE - 1) tl = NTILE - 1;
        #pragma unroll
        for (int j = 0; j < 4; ++j) {
            int colloc = j * 4 + lk;             // 0..15 local col
            int kb = (lc * 16) ^ ((colloc & 7) << 4);
            int col = tl * 64 + strip + colloc;
            if (col > Cc - 1) col = Cc - 1;
            const unsigned short* src = wn + ((size_t)col << 7) + (kb >> 1);
            __builtin_amdgcn_global_load_lds(
                (const __attribute__((address_space(1))) void*)src,
                (__attribute__((address_space(3))) void*)(&swb[w][buf][j * 512]),
                16, 0, 0);
        }
    };

    STAGE(0, 0);
    STAGE(1, 1);
    for (int i = 0; i < ntm; ++i) {
        // wait until only the NEXT stage's 4 loads are outstanding -> current buf ready
        asm volatile("s_waitcnt vmcnt(4)" ::: "memory");
        const unsigned short* bb = &swb[w][i & 1][0];
        short8 bfr[4];
        #pragma unroll
        for (int kc = 0; kc < 4; ++kc) {
            int rkb = (kc * 64 + lk * 16) ^ ((lc & 7) << 4);
            bfr[kc] = *reinterpret_cast<const short8*>(bb + lc * 128 + (rkb >> 1));
        }
        // fragment regs loaded; safe to overwrite this buffer with tile i+2
        asm volatile("s_waitcnt lgkmcnt(0)" ::: "memory");
        STAGE(i & 1, i + 2);

        f32x4 acc[4];
        #pragma unroll
        for (int sm = 0; sm < 4; ++sm) acc[sm] = (f32x4){0.f, 0.f, 0.f, 0.f};
        #pragma unroll
        for (int kc = 0; kc < 4; ++kc)
            #pragma unroll
            for (int sm = 0; sm < 4; ++sm)
                acc[sm] = __builtin_amdgcn_mfma_f32_16x16x32_bf16(
                    afrag[sm][kc], bfr[kc], acc[sm], 0, 0, 0);

        const int c0t = (split + i * NSPL) * 64;
        if (c0t + strip < Cc) {                  // 16-col granularity; 50000 % 16 == 0
            #pragma unroll
            for (int sm = 0; sm < 4; ++sm)
                #pragma unroll
                for (int r = 0; r < 4; ++r)
                    sacc[sm][r] += __builtin_amdgcn_exp2f(
                        fmaf(acc[sm][r], L2E64, -L2E64));
        }
    }

    // reduce over the wave's 16 col-lanes; C/D layout: col=l&15, row=(l>>4)*4+r
    #pragma unroll
    for (int sm = 0; sm < 4; ++sm)
        #pragma unroll
        for (int r = 0; r < 4; ++r) {
            float v = sacc[sm][r];
            v += __shfl_xor(v, 1); v += __shfl_xor(v, 2);
            v += __shfl_xor(v, 4); v += __shfl_xor(v, 8);
            sacc[sm][r] = v;
        }
    if (lc == 0) {
        #pragma unroll
        for (int sm = 0; sm < 4; ++sm)
            #pragma unroll
            for (int r = 0; r < 4; ++r)
                sred[w][sm * 16 + lk * 4 + r] = sacc[sm][r];
    }
    __syncthreads();
    if (t < 64) {
        float sv = sred[0][t] + sred[1][t] + sred[2][t] + sred[3][t];
        ps[(size_t)split * Bn + r0 + t] = sv;
    }
}

// ---------------- batch-hard triplet: bf16 MFMA self-GEMM + masked max/min ----------------
// (R11-proven version, verbatim)
__launch_bounds__(256, 2)
__global__ void trip_k(const unsigned short* __restrict__ eb, const float* __restrict__ sqn,
                       const int* __restrict__ lab,
                       float* __restrict__ hp, float* __restrict__ hn,
                       float* __restrict__ cnt) {
    __shared__ unsigned short swt[8192];      // 16KB: one 64-col tile, XOR-swizzled
    __shared__ float red[128][2][3];
    const int t = threadIdx.x;
    const int w = t >> 6, l = t & 63;
    const int r0 = blockIdx.x * 128;
    const int split = blockIdx.y;
    const int c0 = split * 64;
    const int rowbase = r0 + (w & 1) * 64;
    const int colb = (w >> 1) * 32;

    #pragma unroll
    for (int j = 0; j < 4; ++j) {
        int col = (w * 4 + j) * 4 + (l >> 4);
        int kb = ((l & 15) * 16) ^ ((col & 7) << 4);
        const unsigned short* src = eb + ((size_t)(c0 + col) << 7) + (kb >> 1);
        __builtin_amdgcn_global_load_lds(
            (const __attribute__((address_space(1))) void*)src,
            (__attribute__((address_space(3))) void*)(&swt[(w * 4 + j) * 512]),
            16, 0, 0);
    }

    short8 afrag[4][4];
    #pragma unroll
    for (int sm = 0; sm < 4; ++sm)
        #pragma unroll
        for (int kc = 0; kc < 4; ++kc) {
            int row = rowbase + sm * 16 + (l & 15);
            int k0 = kc * 32 + (l >> 4) * 8;
            afrag[sm][kc] = *reinterpret_cast<const short8*>(eb + (size_t)row * Dd + k0);
        }

    float rsq[4][4]; int rlb[4][4];
    #pragma unroll
    for (int sm = 0; sm < 4; ++sm)
        #pragma unroll
        for (int r = 0; r < 4; ++r) {
            int row = rowbase + sm * 16 + (l >> 4) * 4 + r;
            rsq[sm][r] = sqn[row];
            rlb[sm][r] = lab[row];
        }
    int cj[2]; float csq[2]; int clb[2];
    #pragma unroll
    for (int sn = 0; sn < 2; ++sn) {
        cj[sn] = c0 + colb + sn * 16 + (l & 15);
        csq[sn] = sqn[cj[sn]];
        clb[sn] = lab[cj[sn]];
    }

    __syncthreads();

    f32x4 acc[4][2];
    #pragma unroll
    for (int sm = 0; sm < 4; ++sm)
        #pragma unroll
        for (int sn = 0; sn < 2; ++sn)
            acc[sm][sn] = (f32x4){0.f, 0.f, 0.f, 0.f};

    #pragma unroll
    for (int kc = 0; kc < 4; ++kc) {
        short8 bfr[2];
        #pragma unroll
        for (int sn = 0; sn < 2; ++sn) {
            int rcol = colb + sn * 16 + (l & 15);
            int rkb = (kc * 64 + (l >> 4) * 16) ^ ((rcol & 7) << 4);
            bfr[sn] = *reinterpret_cast<const short8*>(swt + rcol * 128 + (rkb >> 1));
        }
        #pragma unroll
        for (int sn = 0; sn < 2; ++sn)
            #pragma unroll
            for (int sm = 0; sm < 4; ++sm)
                acc[sm][sn] = __builtin_amdgcn_mfma_f32_16x16x32_bf16(
                    afrag[sm][kc], bfr[sn], acc[sm][sn], 0, 0, 0);
    }

    float vhp[4][4], vhn[4][4], vct[4][4];
    #pragma unroll
    for (int sm = 0; sm < 4; ++sm)
        #pragma unroll
        for (int r = 0; r < 4; ++r) { vhp[sm][r] = 0.f; vhn[sm][r] = 1e30f; vct[sm][r] = 0.f; }

    #pragma unroll
    for (int sm = 0; sm < 4; ++sm)
        #pragma unroll
        for (int r = 0; r < 4; ++r) {
            int rg = rowbase + sm * 16 + (l >> 4) * 4 + r;
            #pragma unroll
            for (int sn = 0; sn < 2; ++sn) {
                float d2 = fmaf(acc[sm][sn][r], -2.f, rsq[sm][r] + csq[sn]);
                float dist = sqrtf(fmaxf(d2, 0.f) + 1e-16f);
                bool same = (rlb[sm][r] == clb[sn]);
                bool psel = same && (rg != cj[sn]);
                if (psel) { vhp[sm][r] = fmaxf(vhp[sm][r], dist); vct[sm][r] += 1.f; }
                if (!same) vhn[sm][r] = fminf(vhn[sm][r], dist);
            }
        }

    #pragma unroll
    for (int sm = 0; sm < 4; ++sm)
        #pragma unroll
        for (int r = 0; r < 4; ++r) {
            float a = vhp[sm][r], b = vhn[sm][r], c = vct[sm][r];
            #pragma unroll
            for (int o = 1; o < 16; o <<= 1) {
                a = fmaxf(a, __shfl_xor(a, o));
                b = fminf(b, __shfl_xor(b, o));
                c += __shfl_xor(c, o);
            }
            if ((l & 15) == 0) {
                int row = (w & 1) * 64 + sm * 16 + (l >> 4) * 4 + r;
                red[row][w >> 1][0] = a;
                red[row][w >> 1][1] = b;
                red[row][w >> 1][2] = c;
            }
        }
    __syncthreads();
    if (t < 128) {
        float a = fmaxf(red[t][0][0], red[t][1][0]);
        float b = fminf(red[t][0][1], red[t][1][1]);
        float c = red[t][0][2] + red[t][1][2];
        hp[(size_t)split * Bn + r0 + t] = a;
        hn[(size_t)split * Bn + r0 + t] = b;
        cnt[(size_t)split * Bn + r0 + t] = c;
    }
}

// ---------------- per-row merge -> per-block partials (32 blocks, 4 lanes/row) ----------------
__launch_bounds__(256)
__global__ void final_k(const float* __restrict__ ps, const float* __restrict__ bx,
                        const float* __restrict__ tg, const float* __restrict__ hp,
                        const float* __restrict__ hn, const float* __restrict__ cnt,
                        float* __restrict__ gpart) {
    __shared__ float sA[4], sT[4], sV[4];
    int t = threadIdx.x;
    int row = blockIdx.x * 64 + (t >> 2);
    int part = t & 3;
    float s = 0.f;
    for (int u = part; u < NSPL; u += 4) s += ps[(size_t)u * Bn + row];
    float a = 0.f, b = 1e30f, c = 0.f;
    for (int u = part; u < TS; u += 4) {
        a = fmaxf(a, hp[(size_t)u * Bn + row]);
        b = fminf(b, hn[(size_t)u * Bn + row]);
        c += cnt[(size_t)u * Bn + row];
    }
    // combine the 4 row-parts (lanes p, p^1, p^2 within aligned 4-lane group)
    s += __shfl_xor(s, 1); s += __shfl_xor(s, 2);
    a = fmaxf(a, __shfl_xor(a, 1)); a = fmaxf(a, __shfl_xor(a, 2));
    b = fminf(b, __shfl_xor(b, 1)); b = fminf(b, __shfl_xor(b, 2));
    c += __shfl_xor(c, 1); c += __shfl_xor(c, 2);

    float arcs = 0.f, tris = 0.f, vals = 0.f;
    if (part == 0) {
        float base = bx[row], targ = tg[row];
        s += __expf(targ - 64.f) - __expf(base - 64.f);
        float lse = 64.f + logf(s);
        arcs = lse - 0.9f * targ - 0.1f * (targ - base) / (float)Cc;
        float tl = fmaxf(a - b + 0.3f, 0.f);
        tris = (c > 0.f) ? tl : 0.f;
        vals = (c > 0.f) ? 1.f : 0.f;
    }

    #pragma unroll
    for (int o = 32; o > 0; o >>= 1) {
        arcs += __shfl_xor(arcs, o);
        tris += __shfl_xor(tris, o);
        vals += __shfl_xor(vals, o);
    }
    int wid = t >> 6, lane = t & 63;
    if (lane == 0) { sA[wid] = arcs; sT[wid] = tris; sV[wid] = vals; }
    __syncthreads();
    if (t == 0) {
        gpart[blockIdx.x * 3 + 0] = sA[0] + sA[1] + sA[2] + sA[3];
        gpart[blockIdx.x * 3 + 1] = sT[0] + sT[1] + sT[2] + sT[3];
        gpart[blockIdx.x * 3 + 2] = sV[0] + sV[1] + sV[2] + sV[3];
    }
}

// ---------------- scalar finish ----------------
__global__ void final2_k(const float* __restrict__ gpart, const float* __restrict__ es,
                         const float* __restrict__ wsum, float* __restrict__ out) {
    int l = threadIdx.x;   // 64
    float x = es[l] * wsum[l] + es[l + 64] * wsum[l + 64];
    #pragma unroll
    for (int o = 32; o > 0; o >>= 1) x += __shfl_xor(x, o);
    if (l == 0) {
        float A = 0.f, T = 0.f, V = 0.f;
        for (int b = 0; b < 32; ++b) {
            A += gpart[b * 3 + 0];
            T += gpart[b * 3 + 1];
            V += gpart[b * 3 + 2];
        }
        float tri = (V > 0.f) ? (T / fmaxf(V, 1.f)) : 0.f;
        out[0] = (A - 6.4f * x / (float)Cc) / (float)Bn + 0.5f * tri;
    }
}

extern "C" void kernel_launch(void* const* d_in, const int* in_sizes, int n_in,
                              void* d_out, int out_size, void* d_ws, size_t ws_size,
                              hipStream_t stream) {
    const float* emb = (const float*)d_in[0];
    const float* W = (const float*)d_in[1];
    const int* lab = (const int*)d_in[2];
    float* out = (float*)d_out;

    unsigned short* embn = (unsigned short*)d_ws;          // 2048*128 bf16
    unsigned short* rawb = embn + (size_t)Bn * Dd;         // 2048*128 bf16
    unsigned short* wnb = rawb + (size_t)Bn * Dd;          // 50000*128 bf16
    float* sqn = (float*)(wnb + (size_t)Cc * Dd);          // 2048
    float* ps = sqn + Bn;                                  // NSPL*2048
    float* bx = ps + (size_t)NSPL * Bn;                    // 2048
    float* tg = bx + Bn;                                   // 2048
    float* hp = tg + Bn;                                   // TS*2048
    float* hn = hp + (size_t)TS * Bn;                      // TS*2048
    float* ct = hn + (size_t)TS * Bn;                      // TS*2048
    float* esum = ct + (size_t)TS * Bn;                    // 128
    float* wsum = esum + 128;                              // 128
    float* gpart = wsum + 128;                             // 96

    norm_all<<<256 + Cc / 8, 256, 0, stream>>>(emb, W, embn, rawb, sqn, wnb, esum);
    aux_k<<<272 + Bn / 4, 256, 0, stream>>>(embn, wnb, lab, esum, wsum, bx, tg);
    arc_main<<<dim3(32, NSPL), 256, 0, stream>>>(embn, wnb, ps);
    trip_k<<<dim3(16, TS), 256, 0, stream>>>(rawb, sqn, lab, hp, hn, ct);
    final_k<<<32, 256, 0, stream>>>(ps, bx, tg, hp, hn, ct, gpart);
    final2_k<<<1, 64, 0, stream>>>(gpart, esum, wsum, out);
}

// Round 14
// 80.712 us; speedup vs baseline: 1.6805x; 1.0302x over previous
//
#include <hip/hip_runtime.h>
#include <math.h>

#define Bn 2048
#define Dd 128
#define Cc 50000
#define NSPL 24     // arc col-splits; grid (32 row-blocks x 24) = 768 = 3/CU exact
#define NTILE 782   // ceil(50000/64)
#define TS 32       // triplet col-splits (64 cols each)

#define COS_Mf 0.8775825618903728f
#define SIN_Mf 0.479425538604203f
#define THf (-0.8775825618903728f)
#define MMf 0.2397127693021015f
#define L2E64 92.33248261689366f   // 64 * log2(e)

typedef __attribute__((ext_vector_type(8))) short short8;
typedef __attribute__((ext_vector_type(4))) float f32x4;

__device__ __forceinline__ unsigned short f2bf(float f) {
    unsigned int u = __float_as_uint(f);
    u += 0x7fffu + ((u >> 16) & 1u);
    return (unsigned short)(u >> 16);
}
__device__ __forceinline__ float bf2f(unsigned short h) {
    return __uint_as_float(((unsigned int)h) << 16);
}

// ---------------- row normalization -> bf16, float4-vectorized (8 rows/block) ----------------
__global__ void norm_all(const float* __restrict__ emb, const float* __restrict__ W,
                         unsigned short* __restrict__ embn, unsigned short* __restrict__ rawb,
                         float* __restrict__ sqn, unsigned short* __restrict__ wnb,
                         float* __restrict__ zp) {
    if (blockIdx.x == 0) zp[threadIdx.x] = 0.f;    // esum|wsum (256 floats)
    int wid = threadIdx.x >> 6;
    int lane = threadIdx.x & 63;
    int half = lane >> 5, l32 = lane & 31;
    int row = blockIdx.x * 8 + wid * 2 + half;
    bool ise = row < Bn;
    int r = ise ? row : row - Bn;
    const float* p = (ise ? emb : W) + (size_t)r * Dd + l32 * 4;
    float4 v = *reinterpret_cast<const float4*>(p);
    float ss = v.x * v.x + v.y * v.y + v.z * v.z + v.w * v.w;
    #pragma unroll
    for (int o = 16; o > 0; o >>= 1) ss += __shfl_xor(ss, o);   // stays within 32-lane half
    float rn = rsqrtf(ss);
    ushort4 q4 = make_ushort4(f2bf(v.x * rn), f2bf(v.y * rn), f2bf(v.z * rn), f2bf(v.w * rn));
    *reinterpret_cast<ushort4*>((ise ? embn : wnb) + (size_t)r * Dd + l32 * 4) = q4;
    if (ise) {
        ushort4 r4 = make_ushort4(f2bf(v.x), f2bf(v.y), f2bf(v.z), f2bf(v.w));
        *reinterpret_cast<ushort4*>(rawb + (size_t)r * Dd + l32 * 4) = r4;
        if (l32 == 0) sqn[r] = ss;
    }
}

// ---------------- column sums (blocks 0..271) + per-row label logits (blocks 272..783) ----------------
__global__ void aux_k(const unsigned short* __restrict__ embn,
                      const unsigned short* __restrict__ wnb,
                      const int* __restrict__ lab,
                      float* __restrict__ esum, float* __restrict__ wsum,
                      float* __restrict__ bx, float* __restrict__ tg) {
    __shared__ float s[16][128];
    int t = threadIdx.x;
    if (blockIdx.x < 272) {
        int rg = t >> 4;
        int cg = (t & 15) * 8;
        const unsigned short* src;
        float* dst;
        int r0, rend;
        if (blockIdx.x < 256) {
            src = wnb; dst = wsum;
            r0 = blockIdx.x * 196;
            rend = r0 + 196; if (rend > Cc) rend = Cc;
        } else {
            src = embn; dst = esum;
            r0 = (blockIdx.x - 256) * 128;
            rend = r0 + 128;
        }
        float acc[8];
        #pragma unroll
        for (int j = 0; j < 8; ++j) acc[j] = 0.f;
        for (int r = r0 + rg; r < rend; r += 16) {
            short8 v = *reinterpret_cast<const short8*>(src + (size_t)r * Dd + cg);
            #pragma unroll
            for (int j = 0; j < 8; ++j) acc[j] += bf2f((unsigned short)v[j]);
        }
        #pragma unroll
        for (int j = 0; j < 8; ++j) s[rg][cg + j] = acc[j];
        __syncthreads();
        if (t < 128) {
            float v = 0.f;
            #pragma unroll
            for (int u = 0; u < 16; ++u) v += s[u][t];
            atomicAdd(&dst[t], v);
        }
    } else {
        int wid = t >> 6, lane = t & 63;
        int row = (blockIdx.x - 272) * 4 + wid;
        int lb = lab[row];
        const unsigned short* e = embn + (size_t)row * Dd;
        const unsigned short* wv = wnb + (size_t)lb * Dd;
        float sv = bf2f(e[lane]) * bf2f(wv[lane]) + bf2f(e[lane + 64]) * bf2f(wv[lane + 64]);
        #pragma unroll
        for (int o = 32; o > 0; o >>= 1) sv += __shfl_xor(sv, o);
        if (lane == 0) {
            float c = sv;
            float s2 = fminf(fmaxf(1.f - c * c, 0.f), 1.f);
            float sine = sqrtf(s2);
            float phi = c * COS_Mf - sine * SIN_Mf;
            phi = (c > THf) ? phi : (c - MMf);
            bx[row] = 64.f * c;
            tg[row] = 64.f * phi;
        }
    }
}

// ---------------- fused bf16-MFMA cosine-GEMM + fixed-max softmax partials ----------------
// Per-wave private async pipeline, depth-3: NO __syncthreads in the K-loop. Each wave
// stages its own 16-col strip into 3 rotating LDS buffers via global_load_lds,
// synchronized by counted s_waitcnt vmcnt(8). Per-lane stage offsets hoisted (loop-
// invariant); per-stage address = uniform tile base + loff -> scalar advance.
// grid (32 row-blocks of 64, NSPL=24 splits) = 768 blocks = 3/CU.
__launch_bounds__(256, 3)
__global__ void arc_main(const unsigned short* __restrict__ en,
                         const unsigned short* __restrict__ wn,
                         float* __restrict__ ps) {
    __shared__ unsigned short swb[4][3][2048];   // [wave][buf][16 cols x 128 k], 48KB
    __shared__ float sred[4][64];
    const int t = threadIdx.x;
    const int w = t >> 6, l = t & 63;
    const int r0 = blockIdx.x * 64;
    const int split = blockIdx.y;
    const int strip = w * 16;                    // wave's 16-col strip within each 64-col tile
    const int lc = l & 15, lk = l >> 4;

    // A panel: 64 rows x 128 k (frag: row=lc, k=lk*8 within kc*32)
    short8 afrag[4][4];
    #pragma unroll
    for (int sm = 0; sm < 4; ++sm)
        #pragma unroll
        for (int kc = 0; kc < 4; ++kc)
            afrag[sm][kc] = *reinterpret_cast<const short8*>(
                en + (size_t)(r0 + sm * 16 + lc) * Dd + kc * 32 + lk * 8);

    float sacc[4][4];
    #pragma unroll
    for (int sm = 0; sm < 4; ++sm)
        #pragma unroll
        for (int r = 0; r < 4; ++r) sacc[sm][r] = 0.f;

    const int ntm = (NTILE - 1 - split) / NSPL + 1;   // 32 or 33

    // loop-invariant per-lane stage offsets (elements); source pre-swizzled (rule-21 pair)
    size_t loff[4];
    #pragma unroll
    for (int j = 0; j < 4; ++j) {
        int colloc = j * 4 + lk;                 // 0..15 local col
        int kb = (lc * 16) ^ ((colloc & 7) << 4);
        loff[j] = ((size_t)(strip + colloc) << 7) + (kb >> 1);
    }

    auto STAGE = [&](unsigned short* buf, int idx) {
        int tl = split + idx * NSPL;
        if (tl > NTILE - 1) tl = NTILE - 1;
        const unsigned short* tb = wn + ((size_t)tl << 13);   // tile base (uniform)
        #pragma unroll
        for (int j = 0; j < 4; ++j) {
            __builtin_amdgcn_global_load_lds(
                (const __attribute__((address_space(1))) void*)(tb + loff[j]),
                (__attribute__((address_space(3))) void*)(buf + j * 512),
                16, 0, 0);
        }
    };

    unsigned short* b0 = &swb[w][0][0];
    unsigned short* b1 = &swb[w][1][0];
    unsigned short* b2 = &swb[w][2][0];

    STAGE(b0, 0);
    STAGE(b1, 1);
    STAGE(b2, 2);

#define ASTEP(BUF, I) {                                                        \
    if ((I) < ntm) {                                                           \
        asm volatile("s_waitcnt vmcnt(8)" ::: "memory");                       \
        short8 bfr[4];                                                         \
        _Pragma("unroll")                                                      \
        for (int kc = 0; kc < 4; ++kc) {                                       \
            int rkb = (kc * 64 + lk * 16) ^ ((lc & 7) << 4);                   \
            bfr[kc] = *reinterpret_cast<const short8*>(BUF + lc * 128 + (rkb >> 1)); \
        }                                                                      \
        asm volatile("s_waitcnt lgkmcnt(0)" ::: "memory");                     \
        STAGE(BUF, (I) + 3);                                                   \
        f32x4 acc[4];                                                          \
        _Pragma("unroll")                                                      \
        for (int sm = 0; sm < 4; ++sm) acc[sm] = (f32x4){0.f, 0.f, 0.f, 0.f};  \
        _Pragma("unroll")                                                      \
        for (int kc = 0; kc < 4; ++kc)                                         \
            _Pragma("unroll")                                                  \
            for (int sm = 0; sm < 4; ++sm)                                     \
                acc[sm] = __builtin_amdgcn_mfma_f32_16x16x32_bf16(             \
                    afrag[sm][kc], bfr[kc], acc[sm], 0, 0, 0);                 \
        const int c0t = (split + (I) * NSPL) * 64;                             \
        if (c0t + strip < Cc) {                                                \
            _Pragma("unroll")                                                  \
            for (int sm = 0; sm < 4; ++sm)                                     \
                _Pragma("unroll")                                              \
                for (int r = 0; r < 4; ++r)                                    \
                    sacc[sm][r] += __builtin_amdgcn_exp2f(                     \
                        fmaf(acc[sm][r], L2E64, -L2E64));                      \
        }                                                                      \
    } }

    for (int ii = 0; ii < 33; ii += 3) {
        ASTEP(b0, ii);
        ASTEP(b1, ii + 1);
        ASTEP(b2, ii + 2);
    }
#undef ASTEP

    // reduce over the wave's 16 col-lanes; C/D layout: col=l&15, row=(l>>4)*4+r
    #pragma unroll
    for (int sm = 0; sm < 4; ++sm)
        #pragma unroll
        for (int r = 0; r < 4; ++r) {
            float v = sacc[sm][r];
            v += __shfl_xor(v, 1); v += __shfl_xor(v, 2);
            v += __shfl_xor(v, 4); v += __shfl_xor(v, 8);
            sacc[sm][r] = v;
        }
    if (lc == 0) {
        #pragma unroll
        for (int sm = 0; sm < 4; ++sm)
            #pragma unroll
            for (int r = 0; r < 4; ++r)
                sred[w][sm * 16 + lk * 4 + r] = sacc[sm][r];
    }
    __syncthreads();
    if (t < 64) {
        float sv = sred[0][t] + sred[1][t] + sred[2][t] + sred[3][t];
        ps[(size_t)split * Bn + r0 + t] = sv;
    }
}

// ---------------- batch-hard triplet: bf16 MFMA self-GEMM + masked max/min ----------------
// (R13-proven version, verbatim)
__launch_bounds__(256, 2)
__global__ void trip_k(const unsigned short* __restrict__ eb, const float* __restrict__ sqn,
                       const int* __restrict__ lab,
                       float* __restrict__ hp, float* __restrict__ hn,
                       float* __restrict__ cnt) {
    __shared__ unsigned short swt[8192];      // 16KB: one 64-col tile, XOR-swizzled
    __shared__ float red[128][2][3];
    const int t = threadIdx.x;
    const int w = t >> 6, l = t & 63;
    const int r0 = blockIdx.x * 128;
    const int split = blockIdx.y;
    const int c0 = split * 64;
    const int rowbase = r0 + (w & 1) * 64;
    const int colb = (w >> 1) * 32;

    #pragma unroll
    for (int j = 0; j < 4; ++j) {
        int col = (w * 4 + j) * 4 + (l >> 4);
        int kb = ((l & 15) * 16) ^ ((col & 7) << 4);
        const unsigned short* src = eb + ((size_t)(c0 + col) << 7) + (kb >> 1);
        __builtin_amdgcn_global_load_lds(
            (const __attribute__((address_space(1))) void*)src,
            (__attribute__((address_space(3))) void*)(&swt[(w * 4 + j) * 512]),
            16, 0, 0);
    }

    short8 afrag[4][4];
    #pragma unroll
    for (int sm = 0; sm < 4; ++sm)
        #pragma unroll
        for (int kc = 0; kc < 4; ++kc) {
            int row = rowbase + sm * 16 + (l & 15);
            int k0 = kc * 32 + (l >> 4) * 8;
            afrag[sm][kc] = *reinterpret_cast<const short8*>(eb + (size_t)row * Dd + k0);
        }

    float rsq[4][4]; int rlb[4][4];
    #pragma unroll
    for (int sm = 0; sm < 4; ++sm)
        #pragma unroll
        for (int r = 0; r < 4; ++r) {
            int row = rowbase + sm * 16 + (l >> 4) * 4 + r;
            rsq[sm][r] = sqn[row];
            rlb[sm][r] = lab[row];
        }
    int cj[2]; float csq[2]; int clb[2];
    #pragma unroll
    for (int sn = 0; sn < 2; ++sn) {
        cj[sn] = c0 + colb + sn * 16 + (l & 15);
        csq[sn] = sqn[cj[sn]];
        clb[sn] = lab[cj[sn]];
    }

    __syncthreads();

    f32x4 acc[4][2];
    #pragma unroll
    for (int sm = 0; sm < 4; ++sm)
        #pragma unroll
        for (int sn = 0; sn < 2; ++sn)
            acc[sm][sn] = (f32x4){0.f, 0.f, 0.f, 0.f};

    #pragma unroll
    for (int kc = 0; kc < 4; ++kc) {
        short8 bfr[2];
        #pragma unroll
        for (int sn = 0; sn < 2; ++sn) {
            int rcol = colb + sn * 16 + (l & 15);
            int rkb = (kc * 64 + (l >> 4) * 16) ^ ((rcol & 7) << 4);
            bfr[sn] = *reinterpret_cast<const short8*>(swt + rcol * 128 + (rkb >> 1));
        }
        #pragma unroll
        for (int sn = 0; sn < 2; ++sn)
            #pragma unroll
            for (int sm = 0; sm < 4; ++sm)
                acc[sm][sn] = __builtin_amdgcn_mfma_f32_16x16x32_bf16(
                    afrag[sm][kc], bfr[sn], acc[sm][sn], 0, 0, 0);
    }

    float vhp[4][4], vhn[4][4], vct[4][4];
    #pragma unroll
    for (int sm = 0; sm < 4; ++sm)
        #pragma unroll
        for (int r = 0; r < 4; ++r) { vhp[sm][r] = 0.f; vhn[sm][r] = 1e30f; vct[sm][r] = 0.f; }

    #pragma unroll
    for (int sm = 0; sm < 4; ++sm)
        #pragma unroll
        for (int r = 0; r < 4; ++r) {
            int rg = rowbase + sm * 16 + (l >> 4) * 4 + r;
            #pragma unroll
            for (int sn = 0; sn < 2; ++sn) {
                float d2 = fmaf(acc[sm][sn][r], -2.f, rsq[sm][r] + csq[sn]);
                float dist = sqrtf(fmaxf(d2, 0.f) + 1e-16f);
                bool same = (rlb[sm][r] == clb[sn]);
                bool psel = same && (rg != cj[sn]);
                if (psel) { vhp[sm][r] = fmaxf(vhp[sm][r], dist); vct[sm][r] += 1.f; }
                if (!same) vhn[sm][r] = fminf(vhn[sm][r], dist);
            }
        }

    #pragma unroll
    for (int sm = 0; sm < 4; ++sm)
        #pragma unroll
        for (int r = 0; r < 4; ++r) {
            float a = vhp[sm][r], b = vhn[sm][r], c = vct[sm][r];
            #pragma unroll
            for (int o = 1; o < 16; o <<= 1) {
                a = fmaxf(a, __shfl_xor(a, o));
                b = fminf(b, __shfl_xor(b, o));
                c += __shfl_xor(c, o);
            }
            if ((l & 15) == 0) {
                int row = (w & 1) * 64 + sm * 16 + (l >> 4) * 4 + r;
                red[row][w >> 1][0] = a;
                red[row][w >> 1][1] = b;
                red[row][w >> 1][2] = c;
            }
        }
    __syncthreads();
    if (t < 128) {
        float a = fmaxf(red[t][0][0], red[t][1][0]);
        float b = fminf(red[t][0][1], red[t][1][1]);
        float c = red[t][0][2] + red[t][1][2];
        hp[(size_t)split * Bn + r0 + t] = a;
        hn[(size_t)split * Bn + r0 + t] = b;
        cnt[(size_t)split * Bn + r0 + t] = c;
    }
}

// ---------------- per-row merge -> per-block partials (32 blocks, 4 lanes/row) ----------------
__launch_bounds__(256)
__global__ void final_k(const float* __restrict__ ps, const float* __restrict__ bx,
                        const float* __restrict__ tg, const float* __restrict__ hp,
                        const float* __restrict__ hn, const float* __restrict__ cnt,
                        float* __restrict__ gpart) {
    __shared__ float sA[4], sT[4], sV[4];
    int t = threadIdx.x;
    int row = blockIdx.x * 64 + (t >> 2);
    int part = t & 3;
    float s = 0.f;
    for (int u = part; u < NSPL; u += 4) s += ps[(size_t)u * Bn + row];
    float a = 0.f, b = 1e30f, c = 0.f;
    for (int u = part; u < TS; u += 4) {
        a = fmaxf(a, hp[(size_t)u * Bn + row]);
        b = fminf(b, hn[(size_t)u * Bn + row]);
        c += cnt[(size_t)u * Bn + row];
    }
    // combine the 4 row-parts (lanes p, p^1, p^2 within aligned 4-lane group)
    s += __shfl_xor(s, 1); s += __shfl_xor(s, 2);
    a = fmaxf(a, __shfl_xor(a, 1)); a = fmaxf(a, __shfl_xor(a, 2));
    b = fminf(b, __shfl_xor(b, 1)); b = fminf(b, __shfl_xor(b, 2));
    c += __shfl_xor(c, 1); c += __shfl_xor(c, 2);

    float arcs = 0.f, tris = 0.f, vals = 0.f;
    if (part == 0) {
        float base = bx[row], targ = tg[row];
        s += __expf(targ - 64.f) - __expf(base - 64.f);
        float lse = 64.f + logf(s);
        arcs = lse - 0.9f * targ - 0.1f * (targ - base) / (float)Cc;
        float tl = fmaxf(a - b + 0.3f, 0.f);
        tris = (c > 0.f) ? tl : 0.f;
        vals = (c > 0.f) ? 1.f : 0.f;
    }

    #pragma unroll
    for (int o = 32; o > 0; o >>= 1) {
        arcs += __shfl_xor(arcs, o);
        tris += __shfl_xor(tris, o);
        vals += __shfl_xor(vals, o);
    }
    int wid = t >> 6, lane = t & 63;
    if (lane == 0) { sA[wid] = arcs; sT[wid] = tris; sV[wid] = vals; }
    __syncthreads();
    if (t == 0) {
        gpart[blockIdx.x * 3 + 0] = sA[0] + sA[1] + sA[2] + sA[3];
        gpart[blockIdx.x * 3 + 1] = sT[0] + sT[1] + sT[2] + sT[3];
        gpart[blockIdx.x * 3 + 2] = sV[0] + sV[1] + sV[2] + sV[3];
    }
}

// ---------------- scalar finish ----------------
__global__ void final2_k(const float* __restrict__ gpart, const float* __restrict__ es,
                         const float* __restrict__ wsum, float* __restrict__ out) {
    int l = threadIdx.x;   // 64
    float x = es[l] * wsum[l] + es[l + 64] * wsum[l + 64];
    #pragma unroll
    for (int o = 32; o > 0; o >>= 1) x += __shfl_xor(x, o);
    if (l == 0) {
        float A = 0.f, T = 0.f, V = 0.f;
        for (int b = 0; b < 32; ++b) {
            A += gpart[b * 3 + 0];
            T += gpart[b * 3 + 1];
            V += gpart[b * 3 + 2];
        }
        float tri = (V > 0.f) ? (T / fmaxf(V, 1.f)) : 0.f;
        out[0] = (A - 6.4f * x / (float)Cc) / (float)Bn + 0.5f * tri;
    }
}

extern "C" void kernel_launch(void* const* d_in, const int* in_sizes, int n_in,
                              void* d_out, int out_size, void* d_ws, size_t ws_size,
                              hipStream_t stream) {
    const float* emb = (const float*)d_in[0];
    const float* W = (const float*)d_in[1];
    const int* lab = (const int*)d_in[2];
    float* out = (float*)d_out;

    unsigned short* embn = (unsigned short*)d_ws;          // 2048*128 bf16
    unsigned short* rawb = embn + (size_t)Bn * Dd;         // 2048*128 bf16
    unsigned short* wnb = rawb + (size_t)Bn * Dd;          // 50000*128 bf16
    float* sqn = (float*)(wnb + (size_t)Cc * Dd);          // 2048
    float* ps = sqn + Bn;                                  // NSPL*2048
    float* bx = ps + (size_t)NSPL * Bn;                    // 2048
    float* tg = bx + Bn;                                   // 2048
    float* hp = tg + Bn;                                   // TS*2048
    float* hn = hp + (size_t)TS * Bn;                      // TS*2048
    float* ct = hn + (size_t)TS * Bn;                      // TS*2048
    float* esum = ct + (size_t)TS * Bn;                    // 128
    float* wsum = esum + 128;                              // 128
    float* gpart = wsum + 128;                             // 96

    norm_all<<<256 + Cc / 8, 256, 0, stream>>>(emb, W, embn, rawb, sqn, wnb, esum);
    aux_k<<<272 + Bn / 4, 256, 0, stream>>>(embn, wnb, lab, esum, wsum, bx, tg);
    arc_main<<<dim3(32, NSPL), 256, 0, stream>>>(embn, wnb, ps);
    trip_k<<<dim3(16, TS), 256, 0, stream>>>(rawb, sqn, lab, hp, hn, ct);
    final_k<<<32, 256, 0, stream>>>(ps, bx, tg, hp, hn, ct, gpart);
    final2_k<<<1, 64, 0, stream>>>(gpart, esum, wsum, out);
}

// Round 15
// 78.865 us; speedup vs baseline: 1.7199x; 1.0234x over previous
//
#include <hip/hip_runtime.h>
#include <math.h>

#define Bn 2048
#define Dd 128
#define Cc 50000
#define NSPL 24     // arc col-splits; grid 768 = 32 row-blocks x 24 splits = 3/CU exact
#define NTILE 782   // ceil(50000/64)
#define TS 32       // triplet col-splits (64 cols each)

#define COS_Mf 0.8775825618903728f
#define SIN_Mf 0.479425538604203f
#define THf (-0.8775825618903728f)
#define MMf 0.2397127693021015f
#define L2E64 92.33248261689366f   // 64 * log2(e)

typedef __attribute__((ext_vector_type(8))) short short8;
typedef __attribute__((ext_vector_type(4))) float f32x4;

__device__ __forceinline__ unsigned short f2bf(float f) {
    unsigned int u = __float_as_uint(f);
    u += 0x7fffu + ((u >> 16) & 1u);
    return (unsigned short)(u >> 16);
}
__device__ __forceinline__ float bf2f(unsigned short h) {
    return __uint_as_float(((unsigned int)h) << 16);
}

// ---------------- row normalization -> bf16, float4-vectorized (8 rows/block) ----------------
__global__ void norm_all(const float* __restrict__ emb, const float* __restrict__ W,
                         unsigned short* __restrict__ embn, unsigned short* __restrict__ rawb,
                         float* __restrict__ sqn, unsigned short* __restrict__ wnb,
                         float* __restrict__ zp) {
    if (blockIdx.x == 0) zp[threadIdx.x] = 0.f;    // esum|wsum (256 floats)
    int wid = threadIdx.x >> 6;
    int lane = threadIdx.x & 63;
    int half = lane >> 5, l32 = lane & 31;
    int row = blockIdx.x * 8 + wid * 2 + half;
    bool ise = row < Bn;
    int r = ise ? row : row - Bn;
    const float* p = (ise ? emb : W) + (size_t)r * Dd + l32 * 4;
    float4 v = *reinterpret_cast<const float4*>(p);
    float ss = v.x * v.x + v.y * v.y + v.z * v.z + v.w * v.w;
    #pragma unroll
    for (int o = 16; o > 0; o >>= 1) ss += __shfl_xor(ss, o);   // stays within 32-lane half
    float rn = rsqrtf(ss);
    ushort4 q4 = make_ushort4(f2bf(v.x * rn), f2bf(v.y * rn), f2bf(v.z * rn), f2bf(v.w * rn));
    *reinterpret_cast<ushort4*>((ise ? embn : wnb) + (size_t)r * Dd + l32 * 4) = q4;
    if (ise) {
        ushort4 r4 = make_ushort4(f2bf(v.x), f2bf(v.y), f2bf(v.z), f2bf(v.w));
        *reinterpret_cast<ushort4*>(rawb + (size_t)r * Dd + l32 * 4) = r4;
        if (l32 == 0) sqn[r] = ss;
    }
}

// ---------------- column sums (blocks 0..271) + per-row label logits (blocks 272..783) ----------------
__global__ void aux_k(const unsigned short* __restrict__ embn,
                      const unsigned short* __restrict__ wnb,
                      const int* __restrict__ lab,
                      float* __restrict__ esum, float* __restrict__ wsum,
                      float* __restrict__ bx, float* __restrict__ tg) {
    __shared__ float s[16][128];
    int t = threadIdx.x;
    if (blockIdx.x < 272) {
        int rg = t >> 4;
        int cg = (t & 15) * 8;
        const unsigned short* src;
        float* dst;
        int r0, rend;
        if (blockIdx.x < 256) {
            src = wnb; dst = wsum;
            r0 = blockIdx.x * 196;
            rend = r0 + 196; if (rend > Cc) rend = Cc;
        } else {
            src = embn; dst = esum;
            r0 = (blockIdx.x - 256) * 128;
            rend = r0 + 128;
        }
        float acc[8];
        #pragma unroll
        for (int j = 0; j < 8; ++j) acc[j] = 0.f;
        for (int r = r0 + rg; r < rend; r += 16) {
            short8 v = *reinterpret_cast<const short8*>(src + (size_t)r * Dd + cg);
            #pragma unroll
            for (int j = 0; j < 8; ++j) acc[j] += bf2f((unsigned short)v[j]);
        }
        #pragma unroll
        for (int j = 0; j < 8; ++j) s[rg][cg + j] = acc[j];
        __syncthreads();
        if (t < 128) {
            float v = 0.f;
            #pragma unroll
            for (int u = 0; u < 16; ++u) v += s[u][t];
            atomicAdd(&dst[t], v);
        }
    } else {
        int wid = t >> 6, lane = t & 63;
        int row = (blockIdx.x - 272) * 4 + wid;
        int lb = lab[row];
        const unsigned short* e = embn + (size_t)row * Dd;
        const unsigned short* wv = wnb + (size_t)lb * Dd;
        float sv = bf2f(e[lane]) * bf2f(wv[lane]) + bf2f(e[lane + 64]) * bf2f(wv[lane + 64]);
        #pragma unroll
        for (int o = 32; o > 0; o >>= 1) sv += __shfl_xor(sv, o);
        if (lane == 0) {
            float c = sv;
            float s2 = fminf(fmaxf(1.f - c * c, 0.f), 1.f);
            float sine = sqrtf(s2);
            float phi = c * COS_Mf - sine * SIN_Mf;
            phi = (c > THf) ? phi : (c - MMf);
            bx[row] = 64.f * c;
            tg[row] = 64.f * phi;
        }
    }
}

// ---------------- fused bf16-MFMA cosine-GEMM + fixed-max softmax partials ----------------
// Per-wave private async pipeline, depth-3 (R14-proven), plus XCD-aware block swizzle:
// 1D grid 768; id = xcd + 8*(rb*3 + sp%3), xcd = sp/3  ->  each XCD hosts only 3 of the
// 24 splits, so its W working set is ~1.6MB and stays resident in the 4MB per-XCD L2.
__launch_bounds__(256, 3)
__global__ void arc_main(const unsigned short* __restrict__ en,
                         const unsigned short* __restrict__ wn,
                         float* __restrict__ ps) {
    __shared__ unsigned short swb[4][3][2048];   // [wave][buf][16 cols x 128 k], 48KB
    __shared__ float sred[4][64];
    const int t = threadIdx.x;
    const int w = t >> 6, l = t & 63;
    const int id = blockIdx.x;
    const int xcd = id & 7, j = id >> 3;         // j in 0..95
    const int r0 = (j / 3) * 64;                 // row-block 0..31
    const int split = xcd * 3 + (j % 3);         // 0..23
    const int strip = w * 16;                    // wave's 16-col strip within each 64-col tile
    const int lc = l & 15, lk = l >> 4;

    // A panel: 64 rows x 128 k (frag: row=lc, k=lk*8 within kc*32)
    short8 afrag[4][4];
    #pragma unroll
    for (int sm = 0; sm < 4; ++sm)
        #pragma unroll
        for (int kc = 0; kc < 4; ++kc)
            afrag[sm][kc] = *reinterpret_cast<const short8*>(
                en + (size_t)(r0 + sm * 16 + lc) * Dd + kc * 32 + lk * 8);

    float sacc[4][4];
    #pragma unroll
    for (int sm = 0; sm < 4; ++sm)
        #pragma unroll
        for (int r = 0; r < 4; ++r) sacc[sm][r] = 0.f;

    const int ntm = (NTILE - 1 - split) / NSPL + 1;   // 32 or 33

    // loop-invariant per-lane stage offsets (elements); source pre-swizzled (rule-21 pair)
    size_t loff[4];
    #pragma unroll
    for (int jj = 0; jj < 4; ++jj) {
        int colloc = jj * 4 + lk;                // 0..15 local col
        int kb = (lc * 16) ^ ((colloc & 7) << 4);
        loff[jj] = ((size_t)(strip + colloc) << 7) + (kb >> 1);
    }

    auto STAGE = [&](unsigned short* buf, int idx) {
        int tl = split + idx * NSPL;
        if (tl > NTILE - 1) tl = NTILE - 1;
        const unsigned short* tb = wn + ((size_t)tl << 13);   // tile base (uniform)
        #pragma unroll
        for (int jj = 0; jj < 4; ++jj) {
            __builtin_amdgcn_global_load_lds(
                (const __attribute__((address_space(1))) void*)(tb + loff[jj]),
                (__attribute__((address_space(3))) void*)(buf + jj * 512),
                16, 0, 0);
        }
    };

    unsigned short* b0 = &swb[w][0][0];
    unsigned short* b1 = &swb[w][1][0];
    unsigned short* b2 = &swb[w][2][0];

    STAGE(b0, 0);
    STAGE(b1, 1);
    STAGE(b2, 2);

#define ASTEP(BUF, I) {                                                        \
    if ((I) < ntm) {                                                           \
        asm volatile("s_waitcnt vmcnt(8)" ::: "memory");                       \
        short8 bfr[4];                                                         \
        _Pragma("unroll")                                                      \
        for (int kc = 0; kc < 4; ++kc) {                                       \
            int rkb = (kc * 64 + lk * 16) ^ ((lc & 7) << 4);                   \
            bfr[kc] = *reinterpret_cast<const short8*>(BUF + lc * 128 + (rkb >> 1)); \
        }                                                                      \
        asm volatile("s_waitcnt lgkmcnt(0)" ::: "memory");                     \
        STAGE(BUF, (I) + 3);                                                   \
        f32x4 acc[4];                                                          \
        _Pragma("unroll")                                                      \
        for (int sm = 0; sm < 4; ++sm) acc[sm] = (f32x4){0.f, 0.f, 0.f, 0.f};  \
        _Pragma("unroll")                                                      \
        for (int kc = 0; kc < 4; ++kc)                                         \
            _Pragma("unroll")                                                  \
            for (int sm = 0; sm < 4; ++sm)                                     \
                acc[sm] = __builtin_amdgcn_mfma_f32_16x16x32_bf16(             \
                    afrag[sm][kc], bfr[kc], acc[sm], 0, 0, 0);                 \
        const int c0t = (split + (I) * NSPL) * 64;                             \
        if (c0t + strip < Cc) {                                                \
            _Pragma("unroll")                                                  \
            for (int sm = 0; sm < 4; ++sm)                                     \
                _Pragma("unroll")                                              \
                for (int r = 0; r < 4; ++r)                                    \
                    sacc[sm][r] += __builtin_amdgcn_exp2f(                     \
                        fmaf(acc[sm][r], L2E64, -L2E64));                      \
        }                                                                      \
    } }

    for (int ii = 0; ii < 33; ii += 3) {
        ASTEP(b0, ii);
        ASTEP(b1, ii + 1);
        ASTEP(b2, ii + 2);
    }
#undef ASTEP

    // reduce over the wave's 16 col-lanes; C/D layout: col=l&15, row=(l>>4)*4+r
    #pragma unroll
    for (int sm = 0; sm < 4; ++sm)
        #pragma unroll
        for (int r = 0; r < 4; ++r) {
            float v = sacc[sm][r];
            v += __shfl_xor(v, 1); v += __shfl_xor(v, 2);
            v += __shfl_xor(v, 4); v += __shfl_xor(v, 8);
            sacc[sm][r] = v;
        }
    if (lc == 0) {
        #pragma unroll
        for (int sm = 0; sm < 4; ++sm)
            #pragma unroll
            for (int r = 0; r < 4; ++r)
                sred[w][sm * 16 + lk * 4 + r] = sacc[sm][r];
    }
    __syncthreads();
    if (t < 64) {
        float sv = sred[0][t] + sred[1][t] + sred[2][t] + sred[3][t];
        ps[(size_t)split * Bn + r0 + t] = sv;
    }
}

// ---------------- batch-hard triplet: bf16 MFMA self-GEMM + masked max/min ----------------
// (R14-proven version, verbatim)
__launch_bounds__(256, 2)
__global__ void trip_k(const unsigned short* __restrict__ eb, const float* __restrict__ sqn,
                       const int* __restrict__ lab,
                       float* __restrict__ hp, float* __restrict__ hn,
                       float* __restrict__ cnt) {
    __shared__ unsigned short swt[8192];      // 16KB: one 64-col tile, XOR-swizzled
    __shared__ float red[128][2][3];
    const int t = threadIdx.x;
    const int w = t >> 6, l = t & 63;
    const int r0 = blockIdx.x * 128;
    const int split = blockIdx.y;
    const int c0 = split * 64;
    const int rowbase = r0 + (w & 1) * 64;
    const int colb = (w >> 1) * 32;

    #pragma unroll
    for (int j = 0; j < 4; ++j) {
        int col = (w * 4 + j) * 4 + (l >> 4);
        int kb = ((l & 15) * 16) ^ ((col & 7) << 4);
        const unsigned short* src = eb + ((size_t)(c0 + col) << 7) + (kb >> 1);
        __builtin_amdgcn_global_load_lds(
            (const __attribute__((address_space(1))) void*)src,
            (__attribute__((address_space(3))) void*)(&swt[(w * 4 + j) * 512]),
            16, 0, 0);
    }

    short8 afrag[4][4];
    #pragma unroll
    for (int sm = 0; sm < 4; ++sm)
        #pragma unroll
        for (int kc = 0; kc < 4; ++kc) {
            int row = rowbase + sm * 16 + (l & 15);
            int k0 = kc * 32 + (l >> 4) * 8;
            afrag[sm][kc] = *reinterpret_cast<const short8*>(eb + (size_t)row * Dd + k0);
        }

    float rsq[4][4]; int rlb[4][4];
    #pragma unroll
    for (int sm = 0; sm < 4; ++sm)
        #pragma unroll
        for (int r = 0; r < 4; ++r) {
            int row = rowbase + sm * 16 + (l >> 4) * 4 + r;
            rsq[sm][r] = sqn[row];
            rlb[sm][r] = lab[row];
        }
    int cj[2]; float csq[2]; int clb[2];
    #pragma unroll
    for (int sn = 0; sn < 2; ++sn) {
        cj[sn] = c0 + colb + sn * 16 + (l & 15);
        csq[sn] = sqn[cj[sn]];
        clb[sn] = lab[cj[sn]];
    }

    __syncthreads();

    f32x4 acc[4][2];
    #pragma unroll
    for (int sm = 0; sm < 4; ++sm)
        #pragma unroll
        for (int sn = 0; sn < 2; ++sn)
            acc[sm][sn] = (f32x4){0.f, 0.f, 0.f, 0.f};

    #pragma unroll
    for (int kc = 0; kc < 4; ++kc) {
        short8 bfr[2];
        #pragma unroll
        for (int sn = 0; sn < 2; ++sn) {
            int rcol = colb + sn * 16 + (l & 15);
            int rkb = (kc * 64 + (l >> 4) * 16) ^ ((rcol & 7) << 4);
            bfr[sn] = *reinterpret_cast<const short8*>(swt + rcol * 128 + (rkb >> 1));
        }
        #pragma unroll
        for (int sn = 0; sn < 2; ++sn)
            #pragma unroll
            for (int sm = 0; sm < 4; ++sm)
                acc[sm][sn] = __builtin_amdgcn_mfma_f32_16x16x32_bf16(
                    afrag[sm][kc], bfr[sn], acc[sm][sn], 0, 0, 0);
    }

    float vhp[4][4], vhn[4][4], vct[4][4];
    #pragma unroll
    for (int sm = 0; sm < 4; ++sm)
        #pragma unroll
        for (int r = 0; r < 4; ++r) { vhp[sm][r] = 0.f; vhn[sm][r] = 1e30f; vct[sm][r] = 0.f; }

    #pragma unroll
    for (int sm = 0; sm < 4; ++sm)
        #pragma unroll
        for (int r = 0; r < 4; ++r) {
            int rg = rowbase + sm * 16 + (l >> 4) * 4 + r;
            #pragma unroll
            for (int sn = 0; sn < 2; ++sn) {
                float d2 = fmaf(acc[sm][sn][r], -2.f, rsq[sm][r] + csq[sn]);
                float dist = sqrtf(fmaxf(d2, 0.f) + 1e-16f);
                bool same = (rlb[sm][r] == clb[sn]);
                bool psel = same && (rg != cj[sn]);
                if (psel) { vhp[sm][r] = fmaxf(vhp[sm][r], dist); vct[sm][r] += 1.f; }
                if (!same) vhn[sm][r] = fminf(vhn[sm][r], dist);
            }
        }

    #pragma unroll
    for (int sm = 0; sm < 4; ++sm)
        #pragma unroll
        for (int r = 0; r < 4; ++r) {
            float a = vhp[sm][r], b = vhn[sm][r], c = vct[sm][r];
            #pragma unroll
            for (int o = 1; o < 16; o <<= 1) {
                a = fmaxf(a, __shfl_xor(a, o));
                b = fminf(b, __shfl_xor(b, o));
                c += __shfl_xor(c, o);
            }
            if ((l & 15) == 0) {
                int row = (w & 1) * 64 + sm * 16 + (l >> 4) * 4 + r;
                red[row][w >> 1][0] = a;
                red[row][w >> 1][1] = b;
                red[row][w >> 1][2] = c;
            }
        }
    __syncthreads();
    if (t < 128) {
        float a = fmaxf(red[t][0][0], red[t][1][0]);
        float b = fminf(red[t][0][1], red[t][1][1]);
        float c = red[t][0][2] + red[t][1][2];
        hp[(size_t)split * Bn + r0 + t] = a;
        hn[(size_t)split * Bn + r0 + t] = b;
        cnt[(size_t)split * Bn + r0 + t] = c;
    }
}

// ---------------- per-row merge -> per-block partials (32 blocks, 4 lanes/row) ----------------
__launch_bounds__(256)
__global__ void final_k(const float* __restrict__ ps, const float* __restrict__ bx,
                        const float* __restrict__ tg, const float* __restrict__ hp,
                        const float* __restrict__ hn, const float* __restrict__ cnt,
                        float* __restrict__ gpart) {
    __shared__ float sA[4], sT[4], sV[4];
    int t = threadIdx.x;
    int row = blockIdx.x * 64 + (t >> 2);
    int part = t & 3;
    float s = 0.f;
    for (int u = part; u < NSPL; u += 4) s += ps[(size_t)u * Bn + row];
    float a = 0.f, b = 1e30f, c = 0.f;
    for (int u = part; u < TS; u += 4) {
        a = fmaxf(a, hp[(size_t)u * Bn + row]);
        b = fminf(b, hn[(size_t)u * Bn + row]);
        c += cnt[(size_t)u * Bn + row];
    }
    // combine the 4 row-parts (lanes p, p^1, p^2 within aligned 4-lane group)
    s += __shfl_xor(s, 1); s += __shfl_xor(s, 2);
    a = fmaxf(a, __shfl_xor(a, 1)); a = fmaxf(a, __shfl_xor(a, 2));
    b = fminf(b, __shfl_xor(b, 1)); b = fminf(b, __shfl_xor(b, 2));
    c += __shfl_xor(c, 1); c += __shfl_xor(c, 2);

    float arcs = 0.f, tris = 0.f, vals = 0.f;
    if (part == 0) {
        float base = bx[row], targ = tg[row];
        s += __expf(targ - 64.f) - __expf(base - 64.f);
        float lse = 64.f + logf(s);
        arcs = lse - 0.9f * targ - 0.1f * (targ - base) / (float)Cc;
        float tl = fmaxf(a - b + 0.3f, 0.f);
        tris = (c > 0.f) ? tl : 0.f;
        vals = (c > 0.f) ? 1.f : 0.f;
    }

    #pragma unroll
    for (int o = 32; o > 0; o >>= 1) {
        arcs += __shfl_xor(arcs, o);
        tris += __shfl_xor(tris, o);
        vals += __shfl_xor(vals, o);
    }
    int wid = t >> 6, lane = t & 63;
    if (lane == 0) { sA[wid] = arcs; sT[wid] = tris; sV[wid] = vals; }
    __syncthreads();
    if (t == 0) {
        gpart[blockIdx.x * 3 + 0] = sA[0] + sA[1] + sA[2] + sA[3];
        gpart[blockIdx.x * 3 + 1] = sT[0] + sT[1] + sT[2] + sT[3];
        gpart[blockIdx.x * 3 + 2] = sV[0] + sV[1] + sV[2] + sV[3];
    }
}

// ---------------- scalar finish ----------------
__global__ void final2_k(const float* __restrict__ gpart, const float* __restrict__ es,
                         const float* __restrict__ wsum, float* __restrict__ out) {
    int l = threadIdx.x;   // 64
    float x = es[l] * wsum[l] + es[l + 64] * wsum[l + 64];
    #pragma unroll
    for (int o = 32; o > 0; o >>= 1) x += __shfl_xor(x, o);
    if (l == 0) {
        float A = 0.f, T = 0.f, V = 0.f;
        for (int b = 0; b < 32; ++b) {
            A += gpart[b * 3 + 0];
            T += gpart[b * 3 + 1];
            V += gpart[b * 3 + 2];
        }
        float tri = (V > 0.f) ? (T / fmaxf(V, 1.f)) : 0.f;
        out[0] = (A - 6.4f * x / (float)Cc) / (float)Bn + 0.5f * tri;
    }
}

extern "C" void kernel_launch(void* const* d_in, const int* in_sizes, int n_in,
                              void* d_out, int out_size, void* d_ws, size_t ws_size,
                              hipStream_t stream) {
    const float* emb = (const float*)d_in[0];
    const float* W = (const float*)d_in[1];
    const int* lab = (const int*)d_in[2];
    float* out = (float*)d_out;

    unsigned short* embn = (unsigned short*)d_ws;          // 2048*128 bf16
    unsigned short* rawb = embn + (size_t)Bn * Dd;         // 2048*128 bf16
    unsigned short* wnb = rawb + (size_t)Bn * Dd;          // 50000*128 bf16
    float* sqn = (float*)(wnb + (size_t)Cc * Dd);          // 2048
    float* ps = sqn + Bn;                                  // NSPL*2048
    float* bx = ps + (size_t)NSPL * Bn;                    // 2048
    float* tg = bx + Bn;                                   // 2048
    float* hp = tg + Bn;                                   // TS*2048
    float* hn = hp + (size_t)TS * Bn;                      // TS*2048
    float* ct = hn + (size_t)TS * Bn;                      // TS*2048
    float* esum = ct + (size_t)TS * Bn;                    // 128
    float* wsum = esum + 128;                              // 128
    float* gpart = wsum + 128;                             // 96

    norm_all<<<256 + Cc / 8, 256, 0, stream>>>(emb, W, embn, rawb, sqn, wnb, esum);
    aux_k<<<272 + Bn / 4, 256, 0, stream>>>(embn, wnb, lab, esum, wsum, bx, tg);
    arc_main<<<768, 256, 0, stream>>>(embn, wnb, ps);
    trip_k<<<dim3(16, TS), 256, 0, stream>>>(rawb, sqn, lab, hp, hn, ct);
    final_k<<<32, 256, 0, stream>>>(ps, bx, tg, hp, hn, ct, gpart);
    final2_k<<<1, 64, 0, stream>>>(gpart, esum, wsum, out);
}